// Round 8
// baseline (10.178 us; speedup 1.0000x reference)
//
#include <hip/hip_runtime.h>
#include <math.h>

// Closed form (derived R2, verified vs full statevector sim in R1):
//   e0 = e2 = e3 = 0;  e1 = -cos^2(1) * cos(pi/2 * w1),  w1 = in[:,4].
//
// R8 = R7 (best, 9.82us) + ONE change: nontemporal LOAD as well.
//   - lane merging of the 20B-stride reads happens in the per-instruction
//     address coalescer, independent of cache hints; input is read-once ->
//     NT avoids L1/L2 allocation churn on both streams.
typedef float floatx4 __attribute__((ext_vector_type(4)));

__global__ __launch_bounds__(256) void qlayer_kernel(
    const float* __restrict__ in, floatx4* __restrict__ out4, int B)
{
    int b = blockIdx.x * blockDim.x + threadIdx.x;
    if (b >= B) return;

    const float w1 = __builtin_nontemporal_load(&in[5 * b + 4]);
    const float c = __cosf(1.5707963267948966f * w1);      // w1 in [0,1)
    const float e1 = -0.2919265817264289f * c;             // -cos^2(1) * c

    floatx4 o = {0.0f, e1, 0.0f, 0.0f};
    __builtin_nontemporal_store(o, &out4[b]);
}

extern "C" void kernel_launch(void* const* d_in, const int* in_sizes, int n_in,
                              void* d_out, int out_size, void* d_ws, size_t ws_size,
                              hipStream_t stream) {
    const float* in = (const float*)d_in[0];
    floatx4* out4 = (floatx4*)d_out;
    const int B = in_sizes[0] / 5;  // (B,5) float32
    const int block = 256;
    const int grid = (B + block - 1) / block;
    qlayer_kernel<<<grid, block, 0, stream>>>(in, out4, B);
}